// Round 1
// baseline (225.686 us; speedup 1.0000x reference)
//
#include <hip/hip_runtime.h>
#include <stdint.h>
#include <stddef.h>

// Problem constants
#define T_SEQ 2048
#define C_DIM 640
#define N_BATCH 8

typedef __bf16 bf16x8 __attribute__((ext_vector_type(8)));
typedef float f32x4 __attribute__((ext_vector_type(4)));

__device__ __forceinline__ unsigned short f2bf(float f) {
  unsigned u = __float_as_uint(f);
  u += 0x7fffu + ((u >> 16) & 1u);   // round-to-nearest-even
  return (unsigned short)(u >> 16);
}
__device__ __forceinline__ float bf2f(unsigned short h) {
  return __uint_as_float(((unsigned)h) << 16);
}

__device__ __forceinline__ void gll16(const unsigned short* src, unsigned short* dst) {
  __builtin_amdgcn_global_load_lds(
      (const __attribute__((address_space(1))) void*)src,
      (__attribute__((address_space(3))) void*)dst, 16, 0, 0);
}

// Stage a 128(rows) x 64(k) bf16 tile into LDS (linear dest, row stride 128B).
// Global source is pre-swizzled (rule #21) so that swizzled ds_reads
// (byte ^= (row&7)<<4) observe logical data. LDS dest is wave-uniform base;
// HW adds lane*16.
__device__ __forceinline__ void stage_tile(const unsigned short* gbase, int ldg,
                                           unsigned short* lbuf, int wave, int lane) {
#pragma unroll
  for (int i = 0; i < 4; ++i) {
    const int o   = i * 4096 + wave * 1024 + lane * 16;  // byte offset in tile
    const int row = o >> 7;
    const int cb  = o & 127;
    const int scb = cb ^ ((row & 7) << 4);               // involution within row
    const unsigned short* src = gbase + (size_t)row * ldg + (scb >> 1);
    unsigned short* dst = lbuf + ((i * 4096 + wave * 1024) >> 1);  // wave-uniform
    gll16(src, dst);
  }
}

// One GEMM, three uses (all operands "row-major, K-contiguous" i.e. B^T layout):
// MODE 0: QKV projection. A=xb(16384x640), B=wb[z](640x640), out bf16 Q/K/V.
// MODE 1: S = Q K^T per batch. A=Q_b, B=K_b (both 2048x640), out bf16, skip ni>mi.
// MODE 2: out = P V^T_t / L + x. A=P_b(2048x2048), B=Vt_b(640x2048), out fp32.
// 128x128 tile, BK=64, 4 waves (2x2), mfma_f32_16x16x32_bf16, acc 4x4 frags/wave.
template <int MODE>
__global__ __launch_bounds__(256) void gemm_k(
    const unsigned short* __restrict__ Abase, const unsigned short* __restrict__ Bbase,
    unsigned short* __restrict__ OutB, float* __restrict__ OutF,
    const float* __restrict__ Lrow, const float* __restrict__ Xres) {
  const int mi = blockIdx.x, ni = blockIdx.y, bz = blockIdx.z;
  if constexpr (MODE == 1) {
    if (ni > mi) return;  // fully-masked causal tile
  }
  __shared__ unsigned short As[2][8192];
  __shared__ unsigned short Bs[2][8192];
  const int tid = threadIdx.x;
  const int wave = tid >> 6, lane = tid & 63;
  const int wm = wave >> 1, wn = wave & 1;

  const unsigned short* Ap;
  const unsigned short* Bp;
  int ldA, ldB, ksteps;
  if constexpr (MODE == 0) {
    Ap = Abase + (size_t)mi * 128 * 640;
    Bp = Bbase + (size_t)bz * 409600 + (size_t)ni * 128 * 640;
    ldA = 640; ldB = 640; ksteps = 10;
  } else if constexpr (MODE == 1) {
    Ap = Abase + (size_t)bz * 1310720 + (size_t)mi * 128 * 640;
    Bp = Bbase + (size_t)bz * 1310720 + (size_t)ni * 128 * 640;
    ldA = 640; ldB = 640; ksteps = 10;
  } else {
    Ap = Abase + (size_t)bz * 4194304 + (size_t)mi * 128 * 2048;
    Bp = Bbase + (size_t)bz * 1310720 + (size_t)ni * 128 * 2048;
    ldA = 2048; ldB = 2048; ksteps = 2 * (mi + 1);  // causal K bound
  }

  f32x4 acc[4][4] = {};

  stage_tile(Ap, ldA, As[0], wave, lane);
  stage_tile(Bp, ldB, Bs[0], wave, lane);
  __syncthreads();

  int cur = 0;
  for (int t = 0; t < ksteps; ++t) {
    if (t + 1 < ksteps) {  // issue next-tile loads BEFORE compute (T3-min)
      stage_tile(Ap + (size_t)(t + 1) * 64, ldA, As[cur ^ 1], wave, lane);
      stage_tile(Bp + (size_t)(t + 1) * 64, ldB, Bs[cur ^ 1], wave, lane);
    }
#pragma unroll
    for (int kk = 0; kk < 2; ++kk) {
      bf16x8 af[4], bfr[4];
#pragma unroll
      for (int mt = 0; mt < 4; ++mt) {
        const int row = wm * 64 + mt * 16 + (lane & 15);
        const int cb  = kk * 64 + ((lane >> 4) << 4);
        af[mt] = *(const bf16x8*)&As[cur][row * 64 + ((cb ^ ((row & 7) << 4)) >> 1)];
      }
#pragma unroll
      for (int nt = 0; nt < 4; ++nt) {
        const int row = wn * 64 + nt * 16 + (lane & 15);
        const int cb  = kk * 64 + ((lane >> 4) << 4);
        bfr[nt] = *(const bf16x8*)&Bs[cur][row * 64 + ((cb ^ ((row & 7) << 4)) >> 1)];
      }
#pragma unroll
      for (int mt = 0; mt < 4; ++mt)
#pragma unroll
        for (int nt = 0; nt < 4; ++nt)
          acc[mt][nt] = __builtin_amdgcn_mfma_f32_16x16x32_bf16(af[mt], bfr[nt],
                                                                acc[mt][nt], 0, 0, 0);
    }
    __syncthreads();  // drains vmcnt (staged tile ready) + protects buffer reuse
    cur ^= 1;
  }

  // Epilogue. C/D frag: col = lane&15, row = (lane>>4)*4 + r  [m89/m91-verified]
#pragma unroll
  for (int mt = 0; mt < 4; ++mt) {
#pragma unroll
    for (int nt = 0; nt < 4; ++nt) {
      const int r0 = wm * 64 + mt * 16 + ((lane >> 4) << 2);
      const int c  = wn * 64 + nt * 16 + (lane & 15);
      if constexpr (MODE == 0) {
        const size_t base = (size_t)bz * 10485760 + (size_t)(mi * 128 + r0) * 640 + ni * 128 + c;
#pragma unroll
        for (int r = 0; r < 4; ++r) OutB[base + (size_t)r * 640] = f2bf(acc[mt][nt][r]);
      } else if constexpr (MODE == 1) {
        const size_t base = (size_t)bz * 4194304 + (size_t)(mi * 128 + r0) * 2048 + ni * 128 + c;
#pragma unroll
        for (int r = 0; r < 4; ++r) OutB[base + (size_t)r * 2048] = f2bf(acc[mt][nt][r]);
      } else {
        const int grow = mi * 128 + r0;
        const size_t base = (size_t)bz * 1310720 + (size_t)grow * 640 + ni * 128 + c;
#pragma unroll
        for (int r = 0; r < 4; ++r) {
          const float l = Lrow[(size_t)bz * 2048 + grow + r];
          OutF[base + (size_t)r * 640] = acc[mt][nt][r] / l + Xres[base + (size_t)r * 640];
        }
      }
    }
  }
}

__global__ void cast_x_k(const float* __restrict__ x, unsigned short* __restrict__ xb, int n4) {
  const int stride = gridDim.x * blockDim.x;
  for (int i = blockIdx.x * blockDim.x + threadIdx.x; i < n4; i += stride) {
    const float4 v = ((const float4*)x)[i];
    ushort4 o;
    o.x = f2bf(v.x); o.y = f2bf(v.y); o.z = f2bf(v.z); o.w = f2bf(v.w);
    ((ushort4*)xb)[i] = o;
  }
}

// w_q gets the 1/sqrt(C) softmax scale folded in.
__global__ void cast_w_k(const float* __restrict__ wq, const float* __restrict__ wk,
                         const float* __restrict__ wv, unsigned short* __restrict__ wb) {
  const int z = blockIdx.y;
  const float* w = (z == 0) ? wq : ((z == 1) ? wk : wv);
  const float s = (z == 0) ? 0.03952847075210474f : 1.0f;  // 1/sqrt(640)
  const int i = blockIdx.x * 256 + threadIdx.x;             // 400 blocks * 256 * 4 = 409600
  const float4 v = ((const float4*)w)[i];
  ushort4 o;
  o.x = f2bf(v.x * s); o.y = f2bf(v.y * s); o.z = f2bf(v.z * s); o.w = f2bf(v.w * s);
  ((ushort4*)(wb + (size_t)z * 409600))[i] = o;
}

// V (b,t,c) -> Vt (b,c,t) so PV's B-operand is K-contiguous.
__global__ void transpose_v(const unsigned short* __restrict__ V,
                            unsigned short* __restrict__ Vt) {
  __shared__ unsigned short tile[32][33];
  const int t0 = blockIdx.x * 32, c0 = blockIdx.y * 32, b = blockIdx.z;
  const unsigned short* Vb = V + (size_t)b * T_SEQ * C_DIM;
  unsigned short* Vtb = Vt + (size_t)b * C_DIM * T_SEQ;
  const int tx = threadIdx.x, ty = threadIdx.y;
#pragma unroll
  for (int i = 0; i < 4; ++i)
    tile[ty + i * 8][tx] = Vb[(size_t)(t0 + ty + i * 8) * C_DIM + c0 + tx];
  __syncthreads();
#pragma unroll
  for (int i = 0; i < 4; ++i)
    Vtb[(size_t)(c0 + ty + i * 8) * T_SEQ + t0 + tx] = tile[tx][ty + i * 8];
}

// Per-row causal softmax, in place over S (bf16): writes UNNORMALIZED exp(s - max)
// and the row sum L; zero-fills cols (r, tile-boundary) so PV diagonal tiles are clean.
__global__ void softmax_k(unsigned short* __restrict__ S, float* __restrict__ Lr) {
  const int r = blockIdx.x, b = blockIdx.y;
  const int n = r + 1;
  unsigned short* row = S + ((size_t)b * T_SEQ + r) * T_SEQ;
  __shared__ float buf[T_SEQ];
  __shared__ float red[4];
  const int tid = threadIdx.x;

  float mx = -1e30f;
  for (int c = tid; c < n; c += 256) {
    const float v = bf2f(row[c]);
    buf[c] = v;
    mx = fmaxf(mx, v);
  }
  for (int o = 32; o; o >>= 1) mx = fmaxf(mx, __shfl_xor(mx, o));
  if ((tid & 63) == 0) red[tid >> 6] = mx;
  __syncthreads();
  mx = fmaxf(fmaxf(red[0], red[1]), fmaxf(red[2], red[3]));

  float sum = 0.f;
  for (int c = tid; c < n; c += 256) {
    const float e = __expf(buf[c] - mx);
    row[c] = f2bf(e);
    sum += e;
  }
  for (int o = 32; o; o >>= 1) sum += __shfl_xor(sum, o);
  __syncthreads();  // red[0..3] reads above must finish before reuse
  if ((tid & 63) == 0) red[tid >> 6] = sum;
  __syncthreads();
  if (tid == 0) Lr[(size_t)b * T_SEQ + r] = red[0] + red[1] + red[2] + red[3];

  const int fill_end = ((r >> 7) + 1) << 7;  // PV k-loop boundary for this row's tile
  for (int c = n + tid; c < fill_end; c += 256) row[c] = 0;
}

extern "C" void kernel_launch(void* const* d_in, const int* in_sizes, int n_in,
                              void* d_out, int out_size, void* d_ws, size_t ws_size,
                              hipStream_t stream) {
  (void)in_sizes; (void)n_in; (void)out_size; (void)ws_size;
  const float* x  = (const float*)d_in[0];
  const float* wq = (const float*)d_in[1];
  const float* wk = (const float*)d_in[2];
  const float* wv = (const float*)d_in[3];
  float* out = (float*)d_out;

  // Workspace layout (bytes, all 256-aligned); total 174,489,600 B
  char* ws = (char*)d_ws;
  unsigned short* xb = (unsigned short*)(ws + 0);          // 16384x640 bf16
  unsigned short* wb = (unsigned short*)(ws + 20971520);   // 3x640x640 bf16 (wq scaled)
  unsigned short* Qb = (unsigned short*)(ws + 23429120);   // Q,K,V contiguous bf16
  unsigned short* Vt = (unsigned short*)(ws + 86343680);   // 8x640x2048 bf16
  float*          Lr = (float*)(ws + 107315200);           // 16384 fp32 row sums
  unsigned short* Sb = (unsigned short*)(ws + 107380736);  // 8x2048x2048 bf16 (S, then P)

  cast_x_k<<<2048, 256, 0, stream>>>(x, xb, 2621440);
  cast_w_k<<<dim3(400, 3), 256, 0, stream>>>(wq, wk, wv, wb);
  // QKV projections: grid (M/128, C/128, 3)
  gemm_k<0><<<dim3(128, 5, 3), 256, 0, stream>>>(xb, wb, Qb, nullptr, nullptr, nullptr);
  transpose_v<<<dim3(64, 20, 8), dim3(32, 8), 0, stream>>>(Qb + (size_t)2 * 10485760, Vt);
  // S = Q K^T (causal tiles only): grid (T/128, T/128, B)
  gemm_k<1><<<dim3(16, 16, 8), 256, 0, stream>>>(Qb, Qb + 10485760, Sb, nullptr, nullptr, nullptr);
  softmax_k<<<dim3(2048, 8), 256, 0, stream>>>(Sb, Lr);
  // out = P Vt / L + x: grid (T/128, C/128, B)
  gemm_k<2><<<dim3(16, 5, 8), 256, 0, stream>>>(Sb, Vt, nullptr, out, Lr, x);
}

// Round 2
// 187.223 us; speedup vs baseline: 1.2054x; 1.2054x over previous
//
#include <hip/hip_runtime.h>
#include <stdint.h>
#include <stddef.h>

// Problem constants
#define T_SEQ 2048
#define C_DIM 640
#define N_BATCH 8

typedef __bf16 bf16x8 __attribute__((ext_vector_type(8)));
typedef float f32x4 __attribute__((ext_vector_type(4)));

__device__ __forceinline__ unsigned short f2bf(float f) {
  unsigned u = __float_as_uint(f);
  u += 0x7fffu + ((u >> 16) & 1u);   // round-to-nearest-even
  return (unsigned short)(u >> 16);
}
__device__ __forceinline__ float bf2f(unsigned short h) {
  return __uint_as_float(((unsigned)h) << 16);
}

__device__ __forceinline__ void gll16(const unsigned short* src, unsigned short* dst) {
  __builtin_amdgcn_global_load_lds(
      (const __attribute__((address_space(1))) void*)src,
      (__attribute__((address_space(3))) void*)dst, 16, 0, 0);
}

// Stage a 128(rows) x 64(k) bf16 tile into LDS (linear dest, row stride 128B).
// Global source is pre-swizzled (rule #21) so that swizzled ds_reads
// (byte ^= (row&7)<<4) observe logical data.
__device__ __forceinline__ void stage_tile(const unsigned short* gbase, int ldg,
                                           unsigned short* lbuf, int wave, int lane) {
#pragma unroll
  for (int i = 0; i < 4; ++i) {
    const int o   = i * 4096 + wave * 1024 + lane * 16;  // byte offset in tile
    const int row = o >> 7;
    const int cb  = o & 127;
    const int scb = cb ^ ((row & 7) << 4);               // involution within row
    const unsigned short* src = gbase + (size_t)row * ldg + (scb >> 1);
    unsigned short* dst = lbuf + ((i * 4096 + wave * 1024) >> 1);  // wave-uniform
    gll16(src, dst);
  }
}

// Decode t in [0,136) -> (mi, ni) with t = mi(mi+1)/2 + ni, ni<=mi.
__device__ __forceinline__ void tri_decode(int t, int& mi, int& ni) {
  int m = (int)((__fsqrt_rn(8.0f * (float)t + 1.0f) - 1.0f) * 0.5f);
  while ((m + 1) * (m + 2) / 2 <= t) ++m;
  while (m * (m + 1) / 2 > t) --m;
  mi = m;
  ni = t - m * (m + 1) / 2;
}

// One GEMM, three uses (all operands "row-major, K-contiguous" i.e. B^T layout):
// MODE 0: QKV projection. A=xb(16384x640), B=wb[z](640x640), out bf16 Q/K/V.
// MODE 1: S = Q K^T per batch. A=Q_b, B=K_b (both 2048x640), out bf16, causal tiles only.
// MODE 2: out = P V^T_t / L + x. A=P_b(2048x2048), B=Vt_b(640x2048), out fp32.
// 128x128 tile, BK=64, 4 waves (2x2), mfma_f32_16x16x32_bf16, acc 4x4 frags/wave.
//
// Grid is LINEAR; logical tile decode applies the bijective XCD swizzle (T1)
// so each XCD owns a contiguous logical chunk, and logical order makes blocks
// sharing the LARGE operand (A-tile) adjacent -> A-tile stays in that XCD's L2.
template <int MODE>
__global__ __launch_bounds__(256) void gemm_k(
    const unsigned short* __restrict__ Abase, const unsigned short* __restrict__ Bbase,
    unsigned short* __restrict__ OutB, float* __restrict__ OutF,
    const float* __restrict__ Lrow, const float* __restrict__ Xres) {
  const int lin = blockIdx.x;
  int mi, ni, bz;
  if constexpr (MODE == 0) {
    // nwg = 1920 = 8 * 240; logical wg = mi*15 + (z*5 + ni)
    const int wg = (lin & 7) * 240 + (lin >> 3);
    mi = wg / 15;
    const int t = wg % 15;
    bz = t / 5;            // weight index z
    ni = t % 5;
  } else if constexpr (MODE == 1) {
    // nwg = 1088 = 8 * 136; logical wg = bz*136 + tri(mi,ni) -> XCD k == batch k
    const int wg = (lin & 7) * 136 + (lin >> 3);
    bz = wg / 136;
    tri_decode(wg % 136, mi, ni);
  } else {
    // nwg = 640 = 8 * 80; logical wg = bz*80 + mi*5 + ni -> XCD k == batch k
    const int wg = (lin & 7) * 80 + (lin >> 3);
    bz = wg / 80;
    const int t = wg % 80;
    mi = t / 5;
    ni = t % 5;
  }

  __shared__ unsigned short As[2][8192];
  __shared__ unsigned short Bs[2][8192];
  const int tid = threadIdx.x;
  const int wave = tid >> 6, lane = tid & 63;
  const int wm = wave >> 1, wn = wave & 1;

  const unsigned short* Ap;
  const unsigned short* Bp;
  int ldA, ldB, ksteps;
  if constexpr (MODE == 0) {
    Ap = Abase + (size_t)mi * 128 * 640;
    Bp = Bbase + (size_t)bz * 409600 + (size_t)ni * 128 * 640;
    ldA = 640; ldB = 640; ksteps = 10;
  } else if constexpr (MODE == 1) {
    Ap = Abase + (size_t)bz * 1310720 + (size_t)mi * 128 * 640;
    Bp = Bbase + (size_t)bz * 1310720 + (size_t)ni * 128 * 640;
    ldA = 640; ldB = 640; ksteps = 10;
  } else {
    Ap = Abase + (size_t)bz * 4194304 + (size_t)mi * 128 * 2048;
    Bp = Bbase + (size_t)bz * 1310720 + (size_t)ni * 128 * 2048;
    ldA = 2048; ldB = 2048; ksteps = 2 * (mi + 1);  // causal K bound
  }

  f32x4 acc[4][4] = {};

  stage_tile(Ap, ldA, As[0], wave, lane);
  stage_tile(Bp, ldB, Bs[0], wave, lane);
  __syncthreads();

  int cur = 0;
  for (int t = 0; t < ksteps; ++t) {
    if (t + 1 < ksteps) {  // issue next-tile loads BEFORE compute (T3-min)
      stage_tile(Ap + (size_t)(t + 1) * 64, ldA, As[cur ^ 1], wave, lane);
      stage_tile(Bp + (size_t)(t + 1) * 64, ldB, Bs[cur ^ 1], wave, lane);
    }
#pragma unroll
    for (int kk = 0; kk < 2; ++kk) {
      bf16x8 af[4], bfr[4];
#pragma unroll
      for (int mt = 0; mt < 4; ++mt) {
        const int row = wm * 64 + mt * 16 + (lane & 15);
        const int cb  = kk * 64 + ((lane >> 4) << 4);
        af[mt] = *(const bf16x8*)&As[cur][row * 64 + ((cb ^ ((row & 7) << 4)) >> 1)];
      }
#pragma unroll
      for (int nt = 0; nt < 4; ++nt) {
        const int row = wn * 64 + nt * 16 + (lane & 15);
        const int cb  = kk * 64 + ((lane >> 4) << 4);
        bfr[nt] = *(const bf16x8*)&Bs[cur][row * 64 + ((cb ^ ((row & 7) << 4)) >> 1)];
      }
#pragma unroll
      for (int mt = 0; mt < 4; ++mt)
#pragma unroll
        for (int nt = 0; nt < 4; ++nt)
          acc[mt][nt] = __builtin_amdgcn_mfma_f32_16x16x32_bf16(af[mt], bfr[nt],
                                                                acc[mt][nt], 0, 0, 0);
    }
    __syncthreads();  // drains vmcnt (staged tile ready) + protects buffer reuse
    cur ^= 1;
  }

  // Epilogue. C/D frag: col = lane&15, row = (lane>>4)*4 + r  [m89/m91-verified]
#pragma unroll
  for (int mt = 0; mt < 4; ++mt) {
#pragma unroll
    for (int nt = 0; nt < 4; ++nt) {
      const int r0 = wm * 64 + mt * 16 + ((lane >> 4) << 2);
      const int c  = wn * 64 + nt * 16 + (lane & 15);
      if constexpr (MODE == 0) {
        const size_t base = (size_t)bz * 10485760 + (size_t)(mi * 128 + r0) * 640 + ni * 128 + c;
#pragma unroll
        for (int r = 0; r < 4; ++r) OutB[base + (size_t)r * 640] = f2bf(acc[mt][nt][r]);
      } else if constexpr (MODE == 1) {
        const size_t base = (size_t)bz * 4194304 + (size_t)(mi * 128 + r0) * 2048 + ni * 128 + c;
#pragma unroll
        for (int r = 0; r < 4; ++r) OutB[base + (size_t)r * 2048] = f2bf(acc[mt][nt][r]);
      } else {
        const int grow = mi * 128 + r0;
        const size_t base = (size_t)bz * 1310720 + (size_t)grow * 640 + ni * 128 + c;
#pragma unroll
        for (int r = 0; r < 4; ++r) {
          const float l = Lrow[(size_t)bz * 2048 + grow + r];
          OutF[base + (size_t)r * 640] = acc[mt][nt][r] / l + Xres[base + (size_t)r * 640];
        }
      }
    }
  }
}

__global__ void cast_x_k(const float* __restrict__ x, unsigned short* __restrict__ xb, int n4) {
  const int stride = gridDim.x * blockDim.x;
  for (int i = blockIdx.x * blockDim.x + threadIdx.x; i < n4; i += stride) {
    const float4 v = ((const float4*)x)[i];
    ushort4 o;
    o.x = f2bf(v.x); o.y = f2bf(v.y); o.z = f2bf(v.z); o.w = f2bf(v.w);
    ((ushort4*)xb)[i] = o;
  }
}

// w_q gets the 1/sqrt(C) softmax scale folded in.
__global__ void cast_w_k(const float* __restrict__ wq, const float* __restrict__ wk,
                         const float* __restrict__ wv, unsigned short* __restrict__ wb) {
  const int z = blockIdx.y;
  const float* w = (z == 0) ? wq : ((z == 1) ? wk : wv);
  const float s = (z == 0) ? 0.03952847075210474f : 1.0f;  // 1/sqrt(640)
  const int i = blockIdx.x * 256 + threadIdx.x;             // 400 blocks * 256 * 4 = 409600
  const float4 v = ((const float4*)w)[i];
  ushort4 o;
  o.x = f2bf(v.x * s); o.y = f2bf(v.y * s); o.z = f2bf(v.z * s); o.w = f2bf(v.w * s);
  ((ushort4*)(wb + (size_t)z * 409600))[i] = o;
}

// V (b,t,c) -> Vt (b,c,t) so PV's B-operand is K-contiguous.
__global__ void transpose_v(const unsigned short* __restrict__ V,
                            unsigned short* __restrict__ Vt) {
  __shared__ unsigned short tile[32][33];
  const int t0 = blockIdx.x * 32, c0 = blockIdx.y * 32, b = blockIdx.z;
  const unsigned short* Vb = V + (size_t)b * T_SEQ * C_DIM;
  unsigned short* Vtb = Vt + (size_t)b * C_DIM * T_SEQ;
  const int tx = threadIdx.x, ty = threadIdx.y;
#pragma unroll
  for (int i = 0; i < 4; ++i)
    tile[ty + i * 8][tx] = Vb[(size_t)(t0 + ty + i * 8) * C_DIM + c0 + tx];
  __syncthreads();
#pragma unroll
  for (int i = 0; i < 4; ++i)
    Vtb[(size_t)(c0 + ty + i * 8) * T_SEQ + t0 + tx] = tile[tx][ty + i * 8];
}

// Per-row causal softmax, in place over S (bf16): writes UNNORMALIZED exp(s - max)
// and the row sum L; zero-fills cols (r, tile-boundary) so PV diagonal tiles are clean.
__global__ void softmax_k(unsigned short* __restrict__ S, float* __restrict__ Lr) {
  const int r = blockIdx.x, b = blockIdx.y;
  const int n = r + 1;
  unsigned short* row = S + ((size_t)b * T_SEQ + r) * T_SEQ;
  __shared__ float buf[T_SEQ];
  __shared__ float red[4];
  const int tid = threadIdx.x;

  float mx = -1e30f;
  for (int c = tid; c < n; c += 256) {
    const float v = bf2f(row[c]);
    buf[c] = v;
    mx = fmaxf(mx, v);
  }
  for (int o = 32; o; o >>= 1) mx = fmaxf(mx, __shfl_xor(mx, o));
  if ((tid & 63) == 0) red[tid >> 6] = mx;
  __syncthreads();
  mx = fmaxf(fmaxf(red[0], red[1]), fmaxf(red[2], red[3]));

  float sum = 0.f;
  for (int c = tid; c < n; c += 256) {
    const float e = __expf(buf[c] - mx);
    row[c] = f2bf(e);
    sum += e;
  }
  for (int o = 32; o; o >>= 1) sum += __shfl_xor(sum, o);
  __syncthreads();  // red[0..3] reads above must finish before reuse
  if ((tid & 63) == 0) red[tid >> 6] = sum;
  __syncthreads();
  if (tid == 0) Lr[(size_t)b * T_SEQ + r] = red[0] + red[1] + red[2] + red[3];

  const int fill_end = ((r >> 7) + 1) << 7;  // PV k-loop boundary for this row's tile
  for (int c = n + tid; c < fill_end; c += 256) row[c] = 0;
}

extern "C" void kernel_launch(void* const* d_in, const int* in_sizes, int n_in,
                              void* d_out, int out_size, void* d_ws, size_t ws_size,
                              hipStream_t stream) {
  (void)in_sizes; (void)n_in; (void)out_size; (void)ws_size;
  const float* x  = (const float*)d_in[0];
  const float* wq = (const float*)d_in[1];
  const float* wk = (const float*)d_in[2];
  const float* wv = (const float*)d_in[3];
  float* out = (float*)d_out;

  // Workspace layout (bytes, all 256-aligned); total 174,489,600 B
  char* ws = (char*)d_ws;
  unsigned short* xb = (unsigned short*)(ws + 0);          // 16384x640 bf16
  unsigned short* wb = (unsigned short*)(ws + 20971520);   // 3x640x640 bf16 (wq scaled)
  unsigned short* Qb = (unsigned short*)(ws + 23429120);   // Q,K,V contiguous bf16
  unsigned short* Vt = (unsigned short*)(ws + 86343680);   // 8x640x2048 bf16
  float*          Lr = (float*)(ws + 107315200);           // 16384 fp32 row sums
  unsigned short* Sb = (unsigned short*)(ws + 107380736);  // 8x2048x2048 bf16 (S, then P)

  cast_x_k<<<2048, 256, 0, stream>>>(x, xb, 2621440);
  cast_w_k<<<dim3(400, 3), 256, 0, stream>>>(wq, wk, wv, wb);
  // QKV projections: 1920 linear blocks, XCD-swizzled, A-tile shared by 15 adjacent
  gemm_k<0><<<1920, 256, 0, stream>>>(xb, wb, Qb, nullptr, nullptr, nullptr);
  transpose_v<<<dim3(64, 20, 8), dim3(32, 8), 0, stream>>>(Qb + (size_t)2 * 10485760, Vt);
  // S = Q K^T (causal tiles only): 1088 linear blocks, one batch per XCD
  gemm_k<1><<<1088, 256, 0, stream>>>(Qb, Qb + 10485760, Sb, nullptr, nullptr, nullptr);
  softmax_k<<<dim3(2048, 8), 256, 0, stream>>>(Sb, Lr);
  // out = P Vt / L + x: 640 linear blocks, one batch per XCD, P-tile shared by 5 adjacent
  gemm_k<2><<<640, 256, 0, stream>>>(Sb, Vt, nullptr, out, Lr, x);
}